// Round 5
// baseline (185.078 us; speedup 1.0000x reference)
//
#include <hip/hip_runtime.h>

#define N_PTS 2048
#define BATCH 64
#define STRIPS (N_PTS / 32)

typedef _Float16 half8 __attribute__((ext_vector_type(8)));
typedef float floatx16 __attribute__((ext_vector_type(16)));

// ws layout: Pg (aug f16, 16B/pt), Qg, Z (16B zeros)
#define AUG_BYTES ((size_t)BATCH * N_PTS * 16)
#define WS_NEED (2 * AUG_BYTES + 16)

__device__ __forceinline__ half8 u2h(uint4 u) {
    union { uint4 u; half8 h; } w; w.u = u; return w.h;
}

// Build augmented f16 arrays: per point [v0,v1,v2,v3, -|v|^2/2, 0,0,0].
// grid: 2*BATCH*N_PTS/256 = 1024 blocks x 256.
__global__ __launch_bounds__(256) void prep_kernel(
        const float4* __restrict__ p, const float4* __restrict__ q,
        uint4* __restrict__ Pg, uint4* __restrict__ Qg, uint4* __restrict__ Z) {
    const int gid  = blockIdx.x * 256 + threadIdx.x;
    const int side = gid >= BATCH * N_PTS;
    const int idx  = side ? gid - BATCH * N_PTS : gid;
    const float4 v = (side ? q : p)[idx];
    const float s  = v.x * v.x + v.y * v.y + v.z * v.z + v.w * v.w;
    union { _Float16 h[8]; uint4 u; } w;
    w.h[0] = (_Float16)v.x;  w.h[1] = (_Float16)v.y;
    w.h[2] = (_Float16)v.z;  w.h[3] = (_Float16)v.w;
    w.h[4] = (_Float16)(-0.5f * s);
    w.h[5] = (_Float16)0.0f; w.h[6] = (_Float16)0.0f; w.h[7] = (_Float16)0.0f;
    (side ? Qg : Pg)[idx] = w.u;
    if (gid == 0) *Z = make_uint4(0u, 0u, 0u, 0u);   // zero block for upper lanes
}

// grid: (STRIPS=64, BATCH, 2 dirs), block = 64 (one wave).
// Each block: 32 query rows x all 2048 search cols via 64 MFMA tiles.
// m = p.q - |q|^2/2 from MFMA (aug K=5); min_j d = ps(exact) - 2*max_j m.
__global__ __launch_bounds__(64) void chamfer_mfma_kernel(
        const float4* __restrict__ p, const float4* __restrict__ q,
        const uint4* __restrict__ Pg, const uint4* __restrict__ Qg,
        const uint4* __restrict__ Z, float* __restrict__ out) {
    const int lane  = threadIdx.x;
    const int strip = blockIdx.x;
    const int b     = blockIdx.y;
    const int dir   = blockIdx.z;
    const bool lo   = lane < 32;

    const uint4*  __restrict__ Ag  = (dir ? Qg : Pg) + (size_t)b * N_PTS;
    const uint4*  __restrict__ Bg  = (dir ? Pg : Qg) + (size_t)b * N_PTS;
    const float4* __restrict__ Afp = (dir ? q : p) + (size_t)b * N_PTS;
    const float4* __restrict__ Bfp = (dir ? p : q) + (size_t)b * N_PTS;

    const int row0 = strip * 32;

    // A fragment: rows row0..row0+31 at k=0..7 (lanes 0-31); k=8..15 zero.
    uint4 av = make_uint4(0u, 0u, 0u, 0u);
    float ps = 0.0f;
    if (lo) {
        av = Ag[row0 + lane];
        av.z = (av.z & 0xFFFF0000u) | 0x3C00u;   // k4 <- f16(1.0)
        const float4 pv = Afp[row0 + lane];
        ps = pv.x * pv.x + pv.y * pv.y + pv.z * pv.z + pv.w * pv.w;  // exact fp32
    }
    const half8 a8 = u2h(av);

    // B supply: lower lanes stream cols, upper lanes re-read the zero block.
    const uint4* __restrict__ bbase = lo ? Bg : Z;
    int boff        = lo ? lane : 0;
    const int bstep = lo ? 32 : 0;

    floatx16 zeroc, rmax;
#pragma unroll
    for (int i = 0; i < 16; ++i) { zeroc[i] = 0.0f; rmax[i] = -3.4e38f; }

#pragma unroll 1
    for (int t = 0; t < STRIPS; t += 2) {
        const uint4 b0 = bbase[boff];
        const uint4 b1 = bbase[boff + bstep];
        boff += 2 * bstep;
        const floatx16 d0 = __builtin_amdgcn_mfma_f32_32x32x16_f16(a8, u2h(b0), zeroc, 0, 0, 0);
        const floatx16 d1 = __builtin_amdgcn_mfma_f32_32x32x16_f16(a8, u2h(b1), zeroc, 0, 0, 0);
#pragma unroll
        for (int i = 0; i < 16; ++i)
            rmax[i] = fmaxf(fmaxf(rmax[i], d0[i]), d1[i]);   // -> v_max3_f32
    }

    // max over the 32 cols held by the lanes of each half (rows don't depend
    // on lane&31: row = (i&3) + 8*(i>>2) + 4*(lane>>5))
#pragma unroll
    for (int i = 0; i < 16; ++i) {
        float v = rmax[i];
        v = fmaxf(v, __shfl_xor(v, 1, 64));
        v = fmaxf(v, __shfl_xor(v, 2, 64));
        v = fmaxf(v, __shfl_xor(v, 4, 64));
        v = fmaxf(v, __shfl_xor(v, 8, 64));
        v = fmaxf(v, __shfl_xor(v, 16, 64));
        rmax[i] = v;
    }
    float s = 0.0f;
#pragma unroll
    for (int i = 0; i < 16; ++i) s += rmax[i];
    s *= -2.0f;                       // -2 * sum of this half's 16 row-maxes
    s += __shfl_xor(s, 32, 64);       // both halves -> all 32 rows

    float pst = ps;                   // sum of exact |p|^2 over the 32 rows
    pst += __shfl_xor(pst, 1, 64);
    pst += __shfl_xor(pst, 2, 64);
    pst += __shfl_xor(pst, 4, 64);
    pst += __shfl_xor(pst, 8, 64);
    pst += __shfl_xor(pst, 16, 64);
    pst += __shfl_xor(pst, 32, 64);

    if (lane == 0) atomicAdd(out, s + pst);

    // fused jet term: one block per batch (dir==0, strip==0)
    if (dir == 0 && strip == 0) {
        float ax = 0.f, ay = 0.f, az = 0.f, aw = 0.f;
        for (int j = lane; j < N_PTS; j += 64) {
            const float4 pv = Afp[j];
            const float4 qv = Bfp[j];
            ax += pv.x - qv.x; ay += pv.y - qv.y;
            az += pv.z - qv.z; aw += pv.w - qv.w;
        }
#pragma unroll
        for (int off = 32; off > 0; off >>= 1) {
            ax += __shfl_down(ax, off, 64);
            ay += __shfl_down(ay, off, 64);
            az += __shfl_down(az, off, 64);
            aw += __shfl_down(aw, off, 64);
        }
        if (lane == 0) atomicAdd(out, ax * ax + ay * ay + az * az + aw * aw);
    }
}

// ---------- fallback (known-good R2, 80 us) if ws is too small ----------
#define FB_P 2
#define FB_BLK 256
#define FB_QPB (FB_P * FB_BLK)
__global__ __launch_bounds__(FB_BLK) void chamfer_fb_kernel(
        const float4* __restrict__ p, const float4* __restrict__ q,
        float* __restrict__ out) {
    __shared__ float4 sQ[N_PTS];
    __shared__ float4 sQs4[N_PTS / 4];
    __shared__ float  wsum[4];
    __shared__ float4 wacc[4];
    const int tid = threadIdx.x;
    const int b = blockIdx.y, dir = blockIdx.z;
    const float4* __restrict__ Ab = (dir ? q : p) + (size_t)b * N_PTS;
    const float4* __restrict__ Bb = (dir ? p : q) + (size_t)b * N_PTS;
    float* sQsF = (float*)sQs4;
    for (int j = tid; j < N_PTS; j += FB_BLK) {
        const float4 v = Bb[j];
        sQ[j] = v;
        sQsF[j] = v.x * v.x + v.y * v.y + v.z * v.z + v.w * v.w;
    }
    __syncthreads();
    const int base = blockIdx.x * FB_QPB;
    float4 pm[FB_P]; float mn[FB_P]; float psq = 0.0f;
#pragma unroll
    for (int k = 0; k < FB_P; ++k) {
        const float4 pv = Ab[base + tid + k * FB_BLK];
        psq += pv.x * pv.x + pv.y * pv.y + pv.z * pv.z + pv.w * pv.w;
        pm[k] = make_float4(-2.f * pv.x, -2.f * pv.y, -2.f * pv.z, -2.f * pv.w);
        mn[k] = 3.4e38f;
    }
#define DIST(T, QV, QS)                    \
    float T = fmaf(pm[k].x, (QV).x, (QS)); \
    T = fmaf(pm[k].y, (QV).y, T);          \
    T = fmaf(pm[k].z, (QV).z, T);          \
    T = fmaf(pm[k].w, (QV).w, T);
    for (int j = 0; j < N_PTS; j += 4) {
        const float4 qs4 = sQs4[j >> 2];
        const float4 q0 = sQ[j], q1 = sQ[j + 1], q2 = sQ[j + 2], q3 = sQ[j + 3];
#pragma unroll
        for (int k = 0; k < FB_P; ++k) {
            DIST(t0, q0, qs4.x) DIST(t1, q1, qs4.y)
            mn[k] = fminf(fminf(mn[k], t0), t1);
            DIST(t2, q2, qs4.z) DIST(t3, q3, qs4.w)
            mn[k] = fminf(fminf(mn[k], t2), t3);
        }
    }
#undef DIST
    float s = psq;
#pragma unroll
    for (int k = 0; k < FB_P; ++k) s += mn[k];
#pragma unroll
    for (int off = 32; off > 0; off >>= 1) s += __shfl_down(s, off, 64);
    const int lane = tid & 63, wid = tid >> 6;
    if (lane == 0) wsum[wid] = s;
    __syncthreads();
    if (tid == 0) atomicAdd(out, wsum[0] + wsum[1] + wsum[2] + wsum[3]);
    if (dir == 0 && blockIdx.x == 0) {
        float ax = 0.f, ay = 0.f, az = 0.f, aw = 0.f;
        for (int j = tid; j < N_PTS; j += FB_BLK) {
            const float4 pv = Ab[j], qv = sQ[j];
            ax += pv.x - qv.x; ay += pv.y - qv.y;
            az += pv.z - qv.z; aw += pv.w - qv.w;
        }
#pragma unroll
        for (int off = 32; off > 0; off >>= 1) {
            ax += __shfl_down(ax, off, 64);
            ay += __shfl_down(ay, off, 64);
            az += __shfl_down(az, off, 64);
            aw += __shfl_down(aw, off, 64);
        }
        if (lane == 0) wacc[wid] = make_float4(ax, ay, az, aw);
        __syncthreads();
        if (tid == 0) {
            float dx = 0.f, dy = 0.f, dz = 0.f, dw = 0.f;
#pragma unroll
            for (int w = 0; w < 4; ++w) {
                dx += wacc[w].x; dy += wacc[w].y;
                dz += wacc[w].z; dw += wacc[w].w;
            }
            atomicAdd(out, dx * dx + dy * dy + dz * dz + dw * dw);
        }
    }
}

extern "C" void kernel_launch(void* const* d_in, const int* in_sizes, int n_in,
                              void* d_out, int out_size, void* d_ws, size_t ws_size,
                              hipStream_t stream) {
    const float4* p = (const float4*)d_in[0];
    const float4* q = (const float4*)d_in[1];
    float* out = (float*)d_out;

    hipMemsetAsync(out, 0, sizeof(float), stream);
    if (ws_size >= WS_NEED) {
        uint4* Pg = (uint4*)d_ws;
        uint4* Qg = Pg + (size_t)BATCH * N_PTS;
        uint4* Z  = Qg + (size_t)BATCH * N_PTS;
        prep_kernel<<<2 * BATCH * N_PTS / 256, 256, 0, stream>>>(p, q, Pg, Qg, Z);
        chamfer_mfma_kernel<<<dim3(STRIPS, BATCH, 2), 64, 0, stream>>>(p, q, Pg, Qg, Z, out);
    } else {
        chamfer_fb_kernel<<<dim3(N_PTS / FB_QPB, BATCH, 2), FB_BLK, 0, stream>>>(p, q, out);
    }
}

// Round 6
// 139.251 us; speedup vs baseline: 1.3291x; 1.3291x over previous
//
#include <hip/hip_runtime.h>

#define N_PTS 2048
#define BATCH 64
#define MA 2                      // A strips (32 rows each) per wave
#define ROWS (MA * 32)            // 64 rows per wave
#define XBLKS (N_PTS / ROWS)      // 32
#define TILES (N_PTS / 32)       // 64 B tiles of 32 points

typedef _Float16 half8 __attribute__((ext_vector_type(8)));
typedef float floatx16 __attribute__((ext_vector_type(16)));

// ws layout: Pg (aug f16, 16B/pt), Qg
#define AUG_BYTES ((size_t)BATCH * N_PTS * 16)
#define WS_NEED (2 * AUG_BYTES)

__device__ __forceinline__ half8 u2h(uint4 u) {
    union { uint4 u; half8 h; } w; w.u = u; return w.h;
}

// Build augmented f16 arrays: per point [v0,v1,v2,v3, -|v|^2/2, 0,0,0].
__global__ __launch_bounds__(256) void prep_kernel(
        const float4* __restrict__ p, const float4* __restrict__ q,
        uint4* __restrict__ Pg, uint4* __restrict__ Qg) {
    const int gid  = blockIdx.x * 256 + threadIdx.x;
    const int side = gid >= BATCH * N_PTS;
    const int idx  = side ? gid - BATCH * N_PTS : gid;
    const float4 v = (side ? q : p)[idx];
    const float s  = v.x * v.x + v.y * v.y + v.z * v.z + v.w * v.w;
    union { _Float16 h[8]; uint4 u; } w;
    w.h[0] = (_Float16)v.x;  w.h[1] = (_Float16)v.y;
    w.h[2] = (_Float16)v.z;  w.h[3] = (_Float16)v.w;
    w.h[4] = (_Float16)(-0.5f * s);
    w.h[5] = (_Float16)0.0f; w.h[6] = (_Float16)0.0f; w.h[7] = (_Float16)0.0f;
    (side ? Qg : Pg)[idx] = w.u;
}

// grid: (XBLKS=32, BATCH, 2 dirs), block = 64 (one wave).
// Wave owns 64 query rows (2 strips of 32). B tiles (32 pts) stream through
// per-lane VMEM loads with a 4-tile rolling prefetch; hi lanes load the same
// aug data as lo lanes (k=8..15 of A is zero, so their contribution is 0 —
// no masking needed). m = p.q - |q|^2/2 from MFMA; min_j d = ps - 2*max_j m.
__global__ __launch_bounds__(64) void chamfer_mfma_kernel(
        const float4* __restrict__ p, const float4* __restrict__ q,
        const uint4* __restrict__ Pg, const uint4* __restrict__ Qg,
        float* __restrict__ out) {
    const int lane = threadIdx.x;
    const int col  = lane & 31;
    const bool lo  = lane < 32;
    const int strip = blockIdx.x;
    const int b     = blockIdx.y;
    const int dir   = blockIdx.z;

    const uint4*  __restrict__ Ag  = (dir ? Qg : Pg) + (size_t)b * N_PTS;
    const uint4*  __restrict__ Bg  = (dir ? Pg : Qg) + (size_t)b * N_PTS;
    const float4* __restrict__ Afp = (dir ? q : p) + (size_t)b * N_PTS;
    const float4* __restrict__ Bfp = (dir ? p : q) + (size_t)b * N_PTS;

    const int row0 = strip * ROWS;

    // A fragments (lo lanes hold rows, k4 patched to 1.0; hi lanes zero)
    half8 a8[MA];
    float ps = 0.0f;
#pragma unroll
    for (int s = 0; s < MA; ++s) {
        uint4 av = make_uint4(0u, 0u, 0u, 0u);
        if (lo) {
            av = Ag[row0 + 32 * s + lane];
            av.z = (av.z & 0xFFFF0000u) | 0x3C00u;      // k4 <- f16(1.0)
            const float4 pv = Afp[row0 + 32 * s + lane];
            ps += pv.x * pv.x + pv.y * pv.y + pv.z * pv.z + pv.w * pv.w;
        }
        a8[s] = u2h(av);
    }

    floatx16 zeroc, rmax[MA];
#pragma unroll
    for (int i = 0; i < 16; ++i) {
        zeroc[i] = 0.0f;
#pragma unroll
        for (int s = 0; s < MA; ++s) rmax[s][i] = -3.4e38f;
    }

    // 4-tile rolling prefetch over 64 tiles
    const uint4* __restrict__ B0 = Bg + col;
    uint4 f0 = B0[0 * 32];
    uint4 f1 = B0[1 * 32];
    uint4 f2 = B0[2 * 32];
    uint4 f3 = B0[3 * 32];

#pragma unroll 1
    for (int t = 0; t < TILES; t += 2) {
        const uint4 c0 = f0, c1 = f1;
        f0 = f2; f1 = f3;
        int nt = t + 4;
        nt = (nt >= TILES) ? 0 : nt;                    // wrap: harmless reload
        f2 = B0[nt * 32];
        f3 = B0[nt * 32 + 32];

#pragma unroll
        for (int s = 0; s < MA; ++s) {
            const floatx16 d0 = __builtin_amdgcn_mfma_f32_32x32x16_f16(a8[s], u2h(c0), zeroc, 0, 0, 0);
            const floatx16 d1 = __builtin_amdgcn_mfma_f32_32x32x16_f16(a8[s], u2h(c1), zeroc, 0, 0, 0);
#pragma unroll
            for (int i = 0; i < 16; ++i)
                rmax[s][i] = fmaxf(fmaxf(rmax[s][i], d0[i]), d1[i]);  // v_max3
        }
    }

    // epilogue: per strip, per register: max over 32 cols (5-level xor within
    // each half); rows = (i&3)+8*(i>>2)+4*(lane>>5) — lane-half selects row set.
    float tot = 0.0f;
#pragma unroll
    for (int s = 0; s < MA; ++s) {
        float ssum = 0.0f;
#pragma unroll
        for (int i = 0; i < 16; ++i) {
            float v = rmax[s][i];
            v = fmaxf(v, __shfl_xor(v, 1, 64));
            v = fmaxf(v, __shfl_xor(v, 2, 64));
            v = fmaxf(v, __shfl_xor(v, 4, 64));
            v = fmaxf(v, __shfl_xor(v, 8, 64));
            v = fmaxf(v, __shfl_xor(v, 16, 64));
            ssum += v;
        }
        ssum *= -2.0f;                   // -2 * (this half's 16 row-maxes)
        ssum += __shfl_xor(ssum, 32, 64);
        tot += ssum;
    }
    // ps: exact fp32 |p|^2 sum over the wave's rows
    ps += __shfl_xor(ps, 1, 64);
    ps += __shfl_xor(ps, 2, 64);
    ps += __shfl_xor(ps, 4, 64);
    ps += __shfl_xor(ps, 8, 64);
    ps += __shfl_xor(ps, 16, 64);
    ps += __shfl_xor(ps, 32, 64);

    if (lane == 0) atomicAdd(out, tot + ps);

    // fused jet term: one block per batch (dir==0, strip==0)
    if (dir == 0 && strip == 0) {
        float ax = 0.f, ay = 0.f, az = 0.f, aw = 0.f;
        for (int j = lane; j < N_PTS; j += 64) {
            const float4 pv = Afp[j];
            const float4 qv = Bfp[j];
            ax += pv.x - qv.x; ay += pv.y - qv.y;
            az += pv.z - qv.z; aw += pv.w - qv.w;
        }
#pragma unroll
        for (int off = 32; off > 0; off >>= 1) {
            ax += __shfl_down(ax, off, 64);
            ay += __shfl_down(ay, off, 64);
            az += __shfl_down(az, off, 64);
            aw += __shfl_down(aw, off, 64);
        }
        if (lane == 0) atomicAdd(out, ax * ax + ay * ay + az * az + aw * aw);
    }
}

// ---------- fallback (known-good R2, ~80 us) if ws is too small ----------
#define FB_P 2
#define FB_BLK 256
#define FB_QPB (FB_P * FB_BLK)
__global__ __launch_bounds__(FB_BLK) void chamfer_fb_kernel(
        const float4* __restrict__ p, const float4* __restrict__ q,
        float* __restrict__ out) {
    __shared__ float4 sQ[N_PTS];
    __shared__ float4 sQs4[N_PTS / 4];
    __shared__ float  wsum[4];
    __shared__ float4 wacc[4];
    const int tid = threadIdx.x;
    const int b = blockIdx.y, dir = blockIdx.z;
    const float4* __restrict__ Ab = (dir ? q : p) + (size_t)b * N_PTS;
    const float4* __restrict__ Bb = (dir ? p : q) + (size_t)b * N_PTS;
    float* sQsF = (float*)sQs4;
    for (int j = tid; j < N_PTS; j += FB_BLK) {
        const float4 v = Bb[j];
        sQ[j] = v;
        sQsF[j] = v.x * v.x + v.y * v.y + v.z * v.z + v.w * v.w;
    }
    __syncthreads();
    const int base = blockIdx.x * FB_QPB;
    float4 pm[FB_P]; float mn[FB_P]; float psq = 0.0f;
#pragma unroll
    for (int k = 0; k < FB_P; ++k) {
        const float4 pv = Ab[base + tid + k * FB_BLK];
        psq += pv.x * pv.x + pv.y * pv.y + pv.z * pv.z + pv.w * pv.w;
        pm[k] = make_float4(-2.f * pv.x, -2.f * pv.y, -2.f * pv.z, -2.f * pv.w);
        mn[k] = 3.4e38f;
    }
#define DIST(T, QV, QS)                    \
    float T = fmaf(pm[k].x, (QV).x, (QS)); \
    T = fmaf(pm[k].y, (QV).y, T);          \
    T = fmaf(pm[k].z, (QV).z, T);          \
    T = fmaf(pm[k].w, (QV).w, T);
    for (int j = 0; j < N_PTS; j += 4) {
        const float4 qs4 = sQs4[j >> 2];
        const float4 q0 = sQ[j], q1 = sQ[j + 1], q2 = sQ[j + 2], q3 = sQ[j + 3];
#pragma unroll
        for (int k = 0; k < FB_P; ++k) {
            DIST(t0, q0, qs4.x) DIST(t1, q1, qs4.y)
            mn[k] = fminf(fminf(mn[k], t0), t1);
            DIST(t2, q2, qs4.z) DIST(t3, q3, qs4.w)
            mn[k] = fminf(fminf(mn[k], t2), t3);
        }
    }
#undef DIST
    float s = psq;
#pragma unroll
    for (int k = 0; k < FB_P; ++k) s += mn[k];
#pragma unroll
    for (int off = 32; off > 0; off >>= 1) s += __shfl_down(s, off, 64);
    const int lane = tid & 63, wid = tid >> 6;
    if (lane == 0) wsum[wid] = s;
    __syncthreads();
    if (tid == 0) atomicAdd(out, wsum[0] + wsum[1] + wsum[2] + wsum[3]);
    if (dir == 0 && blockIdx.x == 0) {
        float ax = 0.f, ay = 0.f, az = 0.f, aw = 0.f;
        for (int j = tid; j < N_PTS; j += FB_BLK) {
            const float4 pv = Ab[j], qv = sQ[j];
            ax += pv.x - qv.x; ay += pv.y - qv.y;
            az += pv.z - qv.z; aw += pv.w - qv.w;
        }
#pragma unroll
        for (int off = 32; off > 0; off >>= 1) {
            ax += __shfl_down(ax, off, 64);
            ay += __shfl_down(ay, off, 64);
            az += __shfl_down(az, off, 64);
            aw += __shfl_down(aw, off, 64);
        }
        if (lane == 0) wacc[wid] = make_float4(ax, ay, az, aw);
        __syncthreads();
        if (tid == 0) {
            float dx = 0.f, dy = 0.f, dz = 0.f, dw = 0.f;
#pragma unroll
            for (int w = 0; w < 4; ++w) {
                dx += wacc[w].x; dy += wacc[w].y;
                dz += wacc[w].z; dw += wacc[w].w;
            }
            atomicAdd(out, dx * dx + dy * dy + dz * dz + dw * dw);
        }
    }
}

extern "C" void kernel_launch(void* const* d_in, const int* in_sizes, int n_in,
                              void* d_out, int out_size, void* d_ws, size_t ws_size,
                              hipStream_t stream) {
    const float4* p = (const float4*)d_in[0];
    const float4* q = (const float4*)d_in[1];
    float* out = (float*)d_out;

    hipMemsetAsync(out, 0, sizeof(float), stream);
    if (ws_size >= WS_NEED) {
        uint4* Pg = (uint4*)d_ws;
        uint4* Qg = Pg + (size_t)BATCH * N_PTS;
        prep_kernel<<<2 * BATCH * N_PTS / 256, 256, 0, stream>>>(p, q, Pg, Qg);
        chamfer_mfma_kernel<<<dim3(XBLKS, BATCH, 2), 64, 0, stream>>>(p, q, Pg, Qg, out);
    } else {
        chamfer_fb_kernel<<<dim3(N_PTS / FB_QPB, BATCH, 2), FB_BLK, 0, stream>>>(p, q, out);
    }
}

// Round 7
// 128.575 us; speedup vs baseline: 1.4395x; 1.0830x over previous
//
#include <hip/hip_runtime.h>

#define N_PTS 2048
#define BATCH 64
#define MA 2                            // strips (32 rows) per wave
#define WAVES 4                         // waves per block
#define BLK (WAVES * 64)                // 256 threads
#define ROWS_PER_WAVE (MA * 32)         // 64
#define ROWS_PER_BLK (WAVES * ROWS_PER_WAVE)  // 256
#define XBLKS (N_PTS / ROWS_PER_BLK)    // 8
#define TILES (N_PTS / 32)              // 64

typedef _Float16 half8 __attribute__((ext_vector_type(8)));
typedef float floatx16 __attribute__((ext_vector_type(16)));

__device__ __forceinline__ half8 u2h(uint4 u) {
    union { uint4 u; half8 h; } w; w.u = u; return w.h;
}

// augmented f16 vectors, built in-register from fp32:
//   B role: [q0..q3, -|q|^2/2, 0,0,0]   A role: [p0..p3, 1, 0,0,0]
__device__ __forceinline__ uint4 augB(float4 v) {
    const float s = v.x * v.x + v.y * v.y + v.z * v.z + v.w * v.w;
    union { _Float16 h[8]; uint4 u; } w;
    w.h[0] = (_Float16)v.x;  w.h[1] = (_Float16)v.y;
    w.h[2] = (_Float16)v.z;  w.h[3] = (_Float16)v.w;
    w.h[4] = (_Float16)(-0.5f * s);
    w.h[5] = (_Float16)0.0f; w.h[6] = (_Float16)0.0f; w.h[7] = (_Float16)0.0f;
    return w.u;
}
__device__ __forceinline__ uint4 augA(float4 v) {
    union { _Float16 h[8]; uint4 u; } w;
    w.h[0] = (_Float16)v.x;  w.h[1] = (_Float16)v.y;
    w.h[2] = (_Float16)v.z;  w.h[3] = (_Float16)v.w;
    w.h[4] = (_Float16)1.0f;
    w.h[5] = (_Float16)0.0f; w.h[6] = (_Float16)0.0f; w.h[7] = (_Float16)0.0f;
    return w.u;
}

// grid: (XBLKS=8, BATCH, 2 dirs), block = 256 (4 waves).
// Block stages the full augmented search side (2048 pts, 32 KB) in LDS, then
// each wave owns 64 query rows and sweeps 64 B-tiles: 1 ds_read_b128 feeds
// 2 MFMAs (m = p.q - |q|^2/2); min_j d = |p|^2(exact fp32) - 2*max_j m.
// Hi lanes supply k=8..15 of A = 0, so their B values are don't-care.
__global__ __launch_bounds__(BLK, 4) void chamfer_mfma_kernel(
        const float4* __restrict__ p, const float4* __restrict__ q,
        float* __restrict__ out) {
    __shared__ uint4  sB[N_PTS];        // 32 KB augmented search side
    __shared__ float4 wacc[WAVES];      // jet reduction scratch

    const int tid  = threadIdx.x;
    const int lane = tid & 63;
    const int wv   = tid >> 6;
    const int col  = lane & 31;
    const bool lo  = lane < 32;
    const int b    = blockIdx.y;
    const int dir  = blockIdx.z;

    const float4* __restrict__ Afp = (dir ? q : p) + (size_t)b * N_PTS;  // queries
    const float4* __restrict__ Bfp = (dir ? p : q) + (size_t)b * N_PTS;  // search

    // ---- stage augmented B into LDS (coalesced fp32 loads, aug in-register)
    for (int k = tid; k < N_PTS; k += BLK) {
        sB[k] = augB(Bfp[k]);
    }

    // ---- A fragments for this wave's 64 rows (lo lanes; hi lanes zero)
    const int row0 = blockIdx.x * ROWS_PER_BLK + wv * ROWS_PER_WAVE;
    half8 a8[MA];
    float ps = 0.0f;
#pragma unroll
    for (int s = 0; s < MA; ++s) {
        uint4 av = make_uint4(0u, 0u, 0u, 0u);
        if (lo) {
            const float4 pv = Afp[row0 + 32 * s + lane];
            av = augA(pv);
            ps += pv.x * pv.x + pv.y * pv.y + pv.z * pv.z + pv.w * pv.w;  // exact
        }
        a8[s] = u2h(av);
    }

    floatx16 zeroc, rmax[MA];
#pragma unroll
    for (int i = 0; i < 16; ++i) {
        zeroc[i] = 0.0f;
#pragma unroll
        for (int s = 0; s < MA; ++s) rmax[s][i] = -3.4e38f;
    }

    __syncthreads();

    // ---- main sweep: 64 tiles, unrolled x4
#pragma unroll 1
    for (int t = 0; t < TILES; t += 4) {
        uint4 c[4];
#pragma unroll
        for (int u = 0; u < 4; ++u) {
            c[u] = sB[(t + u) * 32 + col];      // ds_read_b128, 2-way broadcast
        }
#pragma unroll
        for (int u = 0; u < 4; u += 2) {
#pragma unroll
            for (int s = 0; s < MA; ++s) {
                const floatx16 d0 = __builtin_amdgcn_mfma_f32_32x32x16_f16(
                    a8[s], u2h(c[u]), zeroc, 0, 0, 0);
                const floatx16 d1 = __builtin_amdgcn_mfma_f32_32x32x16_f16(
                    a8[s], u2h(c[u + 1]), zeroc, 0, 0, 0);
#pragma unroll
                for (int i = 0; i < 16; ++i)
                    rmax[s][i] = fmaxf(fmaxf(rmax[s][i], d0[i]), d1[i]);  // v_max3
            }
        }
    }

    // ---- epilogue (verified in R5/R6, absmax 0):
    // per strip: per-register max over the 32 cols of this lane-half, then
    // sum the 16 row-maxes; row set differs by lane-half -> xor 32 combines.
    float tot = 0.0f;
#pragma unroll
    for (int s = 0; s < MA; ++s) {
        float ssum = 0.0f;
#pragma unroll
        for (int i = 0; i < 16; ++i) {
            float v = rmax[s][i];
            v = fmaxf(v, __shfl_xor(v, 1, 64));
            v = fmaxf(v, __shfl_xor(v, 2, 64));
            v = fmaxf(v, __shfl_xor(v, 4, 64));
            v = fmaxf(v, __shfl_xor(v, 8, 64));
            v = fmaxf(v, __shfl_xor(v, 16, 64));
            ssum += v;
        }
        ssum *= -2.0f;
        ssum += __shfl_xor(ssum, 32, 64);
        tot += ssum;
    }
    ps += __shfl_xor(ps, 1, 64);
    ps += __shfl_xor(ps, 2, 64);
    ps += __shfl_xor(ps, 4, 64);
    ps += __shfl_xor(ps, 8, 64);
    ps += __shfl_xor(ps, 16, 64);
    ps += __shfl_xor(ps, 32, 64);

    if (lane == 0) atomicAdd(out, tot + ps);

    // ---- fused jet term: one block per batch (dir==0, x==0)
    if (dir == 0 && blockIdx.x == 0) {
        float ax = 0.f, ay = 0.f, az = 0.f, aw = 0.f;
        for (int j = tid; j < N_PTS; j += BLK) {
            const float4 pv = Afp[j];
            const float4 qv = Bfp[j];
            ax += pv.x - qv.x; ay += pv.y - qv.y;
            az += pv.z - qv.z; aw += pv.w - qv.w;
        }
#pragma unroll
        for (int off = 32; off > 0; off >>= 1) {
            ax += __shfl_down(ax, off, 64);
            ay += __shfl_down(ay, off, 64);
            az += __shfl_down(az, off, 64);
            aw += __shfl_down(aw, off, 64);
        }
        if (lane == 0) wacc[wv] = make_float4(ax, ay, az, aw);
        __syncthreads();
        if (tid == 0) {
            float dx = 0.f, dy = 0.f, dz = 0.f, dw = 0.f;
#pragma unroll
            for (int w = 0; w < WAVES; ++w) {
                dx += wacc[w].x; dy += wacc[w].y;
                dz += wacc[w].z; dw += wacc[w].w;
            }
            atomicAdd(out, dx * dx + dy * dy + dz * dz + dw * dw);
        }
    }
}

extern "C" void kernel_launch(void* const* d_in, const int* in_sizes, int n_in,
                              void* d_out, int out_size, void* d_ws, size_t ws_size,
                              hipStream_t stream) {
    const float4* p = (const float4*)d_in[0];
    const float4* q = (const float4*)d_in[1];
    float* out = (float*)d_out;

    hipMemsetAsync(out, 0, sizeof(float), stream);
    chamfer_mfma_kernel<<<dim3(XBLKS, BATCH, 2), BLK, 0, stream>>>(p, q, out);
}